// Round 11
// baseline (175.260 us; speedup 1.0000x reference)
//
#include <hip/hip_runtime.h>

#define FLOOR_EPS 1e-6f

typedef float f32x4 __attribute__((ext_vector_type(4)));

constexpr int Bn     = 64;
constexpr int Tn     = 4096;
constexpr int Cn     = 80;
constexpr int G      = Cn / 4;     // 20 float4 channel-groups
constexpr int CH     = 8;          // timesteps per chunk (halved vs r10)
constexpr int KC     = 16;         // chunks per slab
constexpr int SLAB   = CH * KC;    // 128 timesteps per slab
constexpr int P      = Tn / SLAB;  // 32 slabs per row
constexpr int NT     = KC * G;     // 320 threads (5 waves)
constexpr int NCHUNK = Tn / CH;    // 512 chunks per row
constexpr int NWG    = Bn * P;     // 2048 blocks for both kernels

__device__ __forceinline__ void nt_store4(float4* p, float a, float b,
                                          float c, float d) {
    f32x4 v = {a, b, c, d};
    __builtin_nontemporal_store(v, (f32x4*)p);
}

// ---------------- Kernel A: per-slab (128-step) scan, write chunk states ----
// One block per (b,p). Phase 1: stream 8-step chunk EMA summaries. Phase 2:
// 4-round weighted Hillis-Steele (weight d^8, squared each round). Writes
// the slab-LOCAL inclusive state for every 8-step chunk (10.5 MB in ws).
__global__ __launch_bounds__(NT, 6)
void pcen_slabsum_kernel(const float* __restrict__ x,
                         const float* __restrict__ smooth,
                         float4* __restrict__ states)   // [Bn*NCHUNK*G]
{
    __shared__ float4 sc[2][KC][G];

    const int p  = blockIdx.x % P;
    const int b  = blockIdx.x / P;
    const int t  = threadIdx.x;
    const int g  = t % G;            // g fastest -> coalesced 320B runs
    const int kc = t / G;

    const float4 smv = ((const float4*)smooth)[g];
    float w0 = fminf(fmaxf(smv.x, 0.f), 1.f), w1 = fminf(fmaxf(smv.y, 0.f), 1.f);
    float w2 = fminf(fmaxf(smv.z, 0.f), 1.f), w3 = fminf(fmaxf(smv.w, 0.f), 1.f);
    float d0 = 1.f - w0, d1 = 1.f - w1, d2 = 1.f - w2, d3 = 1.f - w3;

    // d^8 via 3 squarings
    float q0 = d0 * d0, q1 = d1 * d1, q2 = d2 * d2, q3 = d3 * d3;
    q0 *= q0; q1 *= q1; q2 *= q2; q3 *= q3;
    q0 *= q0; q1 *= q1; q2 *= q2; q3 *= q3;

    const size_t rowbase = ((size_t)b * Tn + (size_t)p * SLAB + (size_t)kc * CH) * G + g;
    const float4* px = (const float4*)x + rowbase;

    // phase 1: chunk summary (init fold for the very first chunk of the row:
    // e = x0 works because d*x0 + w*x0 == x0)
    const bool fc = (p == 0) && (kc == 0);
    float e0, e1, e2, e3;
    if (fc) { float4 v = px[0]; e0 = v.x; e1 = v.y; e2 = v.z; e3 = v.w; }
    else    { e0 = 0.f; e1 = 0.f; e2 = 0.f; e3 = 0.f; }
    #pragma unroll
    for (int u = 0; u < CH; ++u) {
        float4 v = px[(size_t)u * G];
        e0 = fmaf(d0, e0, w0 * v.x);
        e1 = fmaf(d1, e1, w1 * v.y);
        e2 = fmaf(d2, e2, w2 * v.z);
        e3 = fmaf(d3, e3, w3 * v.w);
    }
    sc[0][kc][g] = make_float4(e0, e1, e2, e3);
    __syncthreads();

    // phase 2: weighted scan over 16 chunks (W starts d^8, squared per round)
    float W0 = q0, W1 = q1, W2 = q2, W3 = q3;
    int src = 0;
    #pragma unroll
    for (int off = 1; off < KC; off <<= 1) {
        float4 v = sc[src][kc][g];
        if (kc >= off) {
            float4 u4 = sc[src][kc - off][g];
            v.x = fmaf(W0, u4.x, v.x);
            v.y = fmaf(W1, u4.y, v.y);
            v.z = fmaf(W2, u4.z, v.z);
            v.w = fmaf(W3, u4.w, v.w);
        }
        sc[src ^ 1][kc][g] = v;
        __syncthreads();
        src ^= 1;
        W0 *= W0; W1 *= W1; W2 *= W2; W3 *= W3;
    }

    // write every chunk's slab-local inclusive state, fully coalesced:
    // index = (b*NCHUNK + p*KC + kc)*G + g = blockIdx.x*NT + t
    states[(size_t)blockIdx.x * NT + t] = sc[src][kc][g];
}

// ---------------- Kernel B: coop row-prefix (32 slabs) + 8-step replay ------
// One block per (b,p) slab, 320 threads (one per (kc,g)). Prologue:
// cooperatively scan the row's 32 slab summaries (two entries per kc-thread,
// 5 rounds, weight d^128) -> Sg[p']. Each thread forms its incoming state
// from ONE LDS read + ONE states load, then replays only 8 steps (halved
// serial chain; 8 independent x loads batch-issue). x is L3-warm from A and
// never retained in registers (r6 spill lesson).
__global__ __launch_bounds__(NT, 6)
void pcen_out_kernel(const float* __restrict__ x,
                     const float* __restrict__ alpha,
                     const float* __restrict__ delta,
                     const float* __restrict__ root,
                     const float* __restrict__ smooth,
                     const float4* __restrict__ states,
                     float* __restrict__ out)
{
    __shared__ float4 sS[2][2 * KC][G];   // 32 scan entries

    const int p  = blockIdx.x % P;
    const int b  = blockIdx.x / P;
    const int t  = threadIdx.x;
    const int g  = t % G;
    const int kc = t / G;                 // owns scan entries kc and KC+kc

    // ---- per-channel params ----
    const float4 smv = ((const float4*)smooth)[g];
    float w0 = fminf(fmaxf(smv.x, 0.f), 1.f), w1 = fminf(fmaxf(smv.y, 0.f), 1.f);
    float w2 = fminf(fmaxf(smv.z, 0.f), 1.f), w3 = fminf(fmaxf(smv.w, 0.f), 1.f);
    float d0 = 1.f - w0, d1 = 1.f - w1, d2 = 1.f - w2, d3 = 1.f - w3;

    // d^8 via 3 squarings
    float q0 = d0 * d0, q1 = d1 * d1, q2 = d2 * d2, q3 = d3 * d3;
    q0 *= q0; q1 *= q1; q2 *= q2; q3 *= q3;
    q0 *= q0; q1 *= q1; q2 *= q2; q3 *= q3;

    // ---- prologue: cooperative scan of the row's 32 slab summaries ----
    // slab p''s local-inclusive summary = states[chunk p'*KC + (KC-1)]
    {
        const size_t rb = (size_t)b * NCHUNK;
        sS[0][kc][g]      = states[(rb + (size_t)kc * KC + (KC - 1)) * G + g];
        sS[0][KC + kc][g] = states[(rb + (size_t)(KC + kc) * KC + (KC - 1)) * G + g];
    }
    __syncthreads();

    // weight starts at d^128 = (d^8)^16: 4 squarings
    float V0 = q0, V1 = q1, V2 = q2, V3 = q3;
    V0 *= V0; V1 *= V1; V2 *= V2; V3 *= V3;
    V0 *= V0; V1 *= V1; V2 *= V2; V3 *= V3;
    V0 *= V0; V1 *= V1; V2 *= V2; V3 *= V3;
    V0 *= V0; V1 *= V1; V2 *= V2; V3 *= V3;
    int src = 0;
    #pragma unroll
    for (int off = 1; off < 2 * KC; off <<= 1) {   // 5 rounds
        float4 v1 = sS[src][kc][g];
        float4 v2 = sS[src][KC + kc][g];
        if (kc >= off) {
            float4 u4 = sS[src][kc - off][g];
            v1.x = fmaf(V0, u4.x, v1.x);
            v1.y = fmaf(V1, u4.y, v1.y);
            v1.z = fmaf(V2, u4.z, v1.z);
            v1.w = fmaf(V3, u4.w, v1.w);
        }
        {   // KC + kc - off >= 0 for every off <= KC
            float4 u4 = sS[src][KC + kc - off][g];
            v2.x = fmaf(V0, u4.x, v2.x);
            v2.y = fmaf(V1, u4.y, v2.y);
            v2.z = fmaf(V2, u4.z, v2.z);
            v2.w = fmaf(V3, u4.w, v2.w);
        }
        sS[src ^ 1][kc][g]      = v1;
        sS[src ^ 1][KC + kc][g] = v2;
        __syncthreads();
        src ^= 1;
        V0 *= V0; V1 *= V1; V2 *= V2; V3 *= V3;
    }
    // sS[src][p'][g] = globally-inclusive state at the end of slab p'

    // ---- incoming state for chunk (p,kc) ----
    const size_t rowbase = ((size_t)b * Tn + ((size_t)p * KC + kc) * CH) * G + g;
    const float4* px = (const float4*)x + rowbase;

    float s0 = 0.f, s1 = 0.f, s2 = 0.f, s3 = 0.f;
    if (p > 0) {
        float4 Sg = sS[src][p - 1][g];
        s0 = Sg.x; s1 = Sg.y; s2 = Sg.z; s3 = Sg.w;
    }
    float m0, m1, m2, m3;
    if (kc == 0) {
        m0 = s0; m1 = s1; m2 = s2; m3 = s3;
    } else {
        float4 ex = states[((size_t)b * NCHUNK + (size_t)p * KC + kc - 1) * G + g];
        // (d^8)^kc via square-and-multiply on 4 bits of kc
        float k0 = 1.f, k1 = 1.f, k2 = 1.f, k3 = 1.f;
        float b0 = q0, b1 = q1, b2 = q2, b3 = q3;
        int kk = kc;
        #pragma unroll
        for (int bit = 0; bit < 4; ++bit) {
            if (kk & 1) { k0 *= b0; k1 *= b1; k2 *= b2; k3 *= b3; }
            b0 *= b0; b1 *= b1; b2 *= b2; b3 *= b3;
            kk >>= 1;
        }
        m0 = fmaf(k0, s0, ex.x);
        m1 = fmaf(k1, s1, ex.y);
        m2 = fmaf(k2, s2, ex.z);
        m3 = fmaf(k3, s3, ex.w);
    }
    if ((p == 0) && (kc == 0)) {   // exact folded init: a_0 = x_0
        float4 v = px[0];
        m0 = v.x; m1 = v.y; m2 = v.z; m3 = v.w;
    }

    // ---- pointwise params ----
    const float4 alv = ((const float4*)alpha)[g];
    const float4 dlv = ((const float4*)delta)[g];
    const float4 rov = ((const float4*)root)[g];
    float nega[4], invr[4], dl[4], sub[4];
    {
        float as[4] = {alv.x, alv.y, alv.z, alv.w};
        float rs[4] = {rov.x, rov.y, rov.z, rov.w};
        dl[0] = dlv.x; dl[1] = dlv.y; dl[2] = dlv.z; dl[3] = dlv.w;
        #pragma unroll
        for (int j = 0; j < 4; ++j) {
            nega[j] = -fminf(as[j], 1.f);
            invr[j] = 1.f / fmaxf(rs[j], 1.f);
            sub[j]  = __expf(invr[j] * __logf(dl[j]));   // delta^(1/r)
        }
    }
    const bool all_sqrt = (invr[0] == 0.5f) & (invr[1] == 0.5f) &
                          (invr[2] == 0.5f) & (invr[3] == 0.5f);

    float4* po = (float4*)out + rowbase;

    // ---- replay: 8 steps, stream x, EMA, pointwise, nt store ----
    if (all_sqrt) {   // root == 2 fast path (wave-uniform)
        #pragma unroll
        for (int u = 0; u < CH; ++u) {
            float4 xv = px[(size_t)u * G];
            m0 = fmaf(d0, m0, w0 * xv.x);
            m1 = fmaf(d1, m1, w1 * xv.y);
            m2 = fmaf(d2, m2, w2 * xv.z);
            m3 = fmaf(d3, m3, w3 * xv.w);
            nt_store4(&po[(size_t)u * G],
                sqrtf(fmaf(xv.x, __expf(nega[0] * __logf(FLOOR_EPS + m0)), dl[0])) - sub[0],
                sqrtf(fmaf(xv.y, __expf(nega[1] * __logf(FLOOR_EPS + m1)), dl[1])) - sub[1],
                sqrtf(fmaf(xv.z, __expf(nega[2] * __logf(FLOOR_EPS + m2)), dl[2])) - sub[2],
                sqrtf(fmaf(xv.w, __expf(nega[3] * __logf(FLOOR_EPS + m3)), dl[3])) - sub[3]);
        }
    } else {
        float w[4] = {w0, w1, w2, w3}, dc[4] = {d0, d1, d2, d3};
        float mm[4] = {m0, m1, m2, m3};
        #pragma unroll
        for (int u = 0; u < CH; ++u) {
            float4 xv = px[(size_t)u * G];
            float xv4[4] = {xv.x, xv.y, xv.z, xv.w};
            float os[4];
            #pragma unroll
            for (int j = 0; j < 4; ++j) {
                mm[j]   = fmaf(dc[j], mm[j], w[j] * xv4[j]);
                float pw = __expf(nega[j] * __logf(FLOOR_EPS + mm[j]));
                float v  = fmaf(xv4[j], pw, dl[j]);
                os[j]    = __expf(invr[j] * __logf(v)) - sub[j];
            }
            nt_store4(&po[(size_t)u * G], os[0], os[1], os[2], os[3]);
        }
    }
}

extern "C" void kernel_launch(void* const* d_in, const int* in_sizes, int n_in,
                              void* d_out, int out_size, void* d_ws, size_t ws_size,
                              hipStream_t stream) {
    const float* x      = (const float*)d_in[0];
    const float* alpha  = (const float*)d_in[1];
    const float* delta  = (const float*)d_in[2];
    const float* root   = (const float*)d_in[3];
    const float* smooth = (const float*)d_in[4];
    float* out = (float*)d_out;

    float4* states = (float4*)d_ws;   // Bn*NCHUNK*G float4 = 10.5 MB

    pcen_slabsum_kernel<<<NWG, NT, 0, stream>>>(x, smooth, states);
    pcen_out_kernel<<<NWG, NT, 0, stream>>>(x, alpha, delta, root, smooth,
                                            states, out);
}